// Round 3
// baseline (1489.362 us; speedup 1.0000x reference)
//
#include <hip/hip_runtime.h>
#include <math.h>

#define B_H   32
#define NSEQ  8192
#define HD    64
#define NOFF  44
#define TILE  64
#define NTHR  256

// DSQG attention: per position n, scores over 44 shifted offsets, softmax,
// then rotated weighted V-sum.  Rotation factored out: with a=p*cos, b=p*sin,
//   out_even = U_even - W_odd,  out_odd = W_even + U_odd,
// where U = sum a_i * v[n-d_i], W = sum b_i * v[n-d_i].

__global__ __launch_bounds__(NTHR) void dsqg_fwd(
    const float* __restrict__ q,
    const float* __restrict__ k,
    const float* __restrict__ v,
    const float* __restrict__ pos_bias,
    const float* __restrict__ se,
    const float* __restrict__ phase,
    float* __restrict__ out)
{
    constexpr int OFFS[NOFF] = {
        0,1,2,3,4,5,6,7,8,9,10,11,12,13,14,15,16,
        17,18,19,20,21,22,23,24,25,26,27,28,29,30,31,32,
        48,64,96,128,192,256,384,512,768,1024,1536};

    __shared__ __align__(16) float qs[TILE * HD];

    const int tid  = threadIdx.x;
    const int lane = tid & 63;
    const int w    = tid >> 6;
    const int bid  = blockIdx.x;
    const int bh   = bid >> 7;        // 128 tiles of 64 positions per (b,h)
    const int tile = bid & 127;
    const int n0   = tile * TILE;
    const int h    = bh & 15;
    const int base = bh * (NSEQ * HD);

    // stage this block's 64 q rows into LDS (broadcast-read later)
    for (int idx = tid; idx < TILE * HD; idx += NTHR)
        qs[idx] = q[base + n0 * HD + idx];
    __syncthreads();

    // per-lane offset: lane i (i<44) owns offset OFFS[i]; computed arithmetically
    int di;
    if (lane < 33) di = lane;
    else { int tt = lane - 33; di = ((((tt & 1) ? 4 : 3) << (tt >> 1)) << 4); }
    const int   iC = (lane < NOFF) ? lane : 0;     // clamped for safe loads
    const float pb = pos_bias[iC * 16 + h];
    const float ph = phase[iC * 16 + h];
    const float cv = cosf(ph);
    const float sv = sinf(ph);
    const float sc = 0.125f;                       // 1/sqrt(64)

    const float4* se4 = (const float4*)se;

    // each wave handles 16 consecutive positions
    for (int t = 0; t < TILE / 4; ++t) {
        const int nl = w * (TILE / 4) + t;
        const int n  = n0 + nl;

        // ---------------- scores: lane i computes s_i ----------------
        const int  rowk  = n - di;
        const bool valid = (lane < NOFF) && (rowk >= 0);
        const float4* kr = (const float4*)(k + base + (valid ? rowk : 0) * HD);
        const float4* qr = (const float4*)(qs + nl * HD);

        float acc = 0.f;   // q . (k[n-d] + se_i)   (fuses qk and qdyn terms)
        #pragma unroll 4
        for (int jj = 0; jj < HD / 4; ++jj) {
            const float4 q4 = qr[jj];                    // LDS broadcast
            const float4 e4 = se4[iC * (HD / 4) + jj];   // L1-hot (11 KB)
            const float4 k4 = kr[jj];                    // scattered rows, L1/L2
            acc += (k4.x + e4.x) * q4.x;
            acc += (k4.y + e4.y) * q4.y;
            acc += (k4.z + e4.z) * q4.z;
            acc += (k4.w + e4.w) * q4.w;
        }
        float s = valid ? fmaf(acc, sc, pb) : -INFINITY;

        // ---------------- softmax across the 44 lanes ----------------
        float m = s;
        #pragma unroll
        for (int mm = 32; mm >= 1; mm >>= 1) m = fmaxf(m, __shfl_xor(m, mm));
        const float e = __expf(s - m);                 // -inf -> 0
        float sum = e;
        #pragma unroll
        for (int mm = 32; mm >= 1; mm >>= 1) sum += __shfl_xor(sum, mm);
        const float p   = e / sum;
        const float pa  = p * cv;
        const float pbs = p * sv;

        // ---------------- PV: lane = head-dim j ----------------
        float U = 0.f, W = 0.f;
        #pragma unroll
        for (int i = 0; i < NOFF; ++i) {
            const int rowv = n - OFFS[i];              // wave-uniform
            if (rowv >= 0) {
                const float ai = __shfl(pa,  i);       // broadcast p*cos
                const float bi = __shfl(pbs, i);       // broadcast p*sin
                const float vv = v[base + rowv * HD + lane];  // coalesced 256B row
                U = fmaf(ai, vv, U);
                W = fmaf(bi, vv, W);
            }
        }
        const float Wx = __shfl_xor(W, 1);
        out[base + n * HD + lane] = U + ((lane & 1) ? Wx : -Wx);
    }
}

extern "C" void kernel_launch(void* const* d_in, const int* in_sizes, int n_in,
                              void* d_out, int out_size, void* d_ws, size_t ws_size,
                              hipStream_t stream) {
    const float* q  = (const float*)d_in[0];
    const float* k  = (const float*)d_in[1];
    const float* v  = (const float*)d_in[2];
    const float* pb = (const float*)d_in[3];
    const float* se = (const float*)d_in[4];
    const float* ph = (const float*)d_in[5];
    float* out = (float*)d_out;

    dim3 grid(B_H * (NSEQ / TILE));   // 32 (b,h) x 128 tiles = 4096 blocks
    dim3 block(NTHR);
    hipLaunchKernelGGL(dsqg_fwd, grid, block, 0, stream,
                       q, k, v, pb, se, ph, out);
}